// Round 9
// baseline (82.119 us; speedup 1.0000x reference)
//
#include <hip/hip_runtime.h>

// Problem constants (B,C,H,W,K) = (32,192,56,56,7)
#define BB 32
#define CC 192
#define HH 56
#define WW 56
#define KS 7
#define HW 3136        // 56*56
#define KK 49
#define CKK 9408       // C*K*K
#define PL 8
#define NCELL (BB * CC * KK)   // 301056 = 1176*256
#define NBC (BB * CC)          // 6144
#define SPAD 32                // stats padding: one 128B line per sample

typedef float f2 __attribute__((ext_vector_type(2)));

// ---------------------------------------------------------------------------
// K0: zero the stats accumulators (replaces in-graph hipMemsetAsync).
// ---------------------------------------------------------------------------
__global__ __launch_bounds__(256) void zero_kernel(float* __restrict__ p) {
    p[blockIdx.x * 256 + threadIdx.x] = 0.f;
}

// ---------------------------------------------------------------------------
// K1: avg pool 56x56 -> 7x7, fused LN0 stats (wave reduce + padded atomics).
// ---------------------------------------------------------------------------
__global__ __launch_bounds__(256) void pool_kernel(const float* __restrict__ x,
                                                   float* __restrict__ p0,
                                                   float* __restrict__ stats0) {
    int idx = blockIdx.x * 256 + threadIdx.x;
    int j = idx % KS;
    int i = (idx / KS) % KS;
    int bc = idx / KK;
    const float* src = x + (size_t)bc * HW + (i * PL) * WW + j * PL;
    float s = 0.f;
#pragma unroll
    for (int a = 0; a < PL; ++a) {
        float4 v0 = *(const float4*)(src + a * WW);
        float4 v1 = *(const float4*)(src + a * WW + 4);
        s += v0.x + v0.y + v0.z + v0.w + v1.x + v1.y + v1.z + v1.w;
    }
    float v = s * (1.f / 64.f);
    p0[idx] = v;

    float sv = v, sq = v * v;
#pragma unroll
    for (int o = 32; o > 0; o >>= 1) {
        sv += __shfl_down(sv, o, 64);
        sq += __shfl_down(sq, o, 64);
    }
    if ((threadIdx.x & 63) == 0) {
        int b = idx / CKK;                    // wave-uniform (64 | 9408)
        atomicAdd(&stats0[b * SPAD + 0], sv);
        atomicAdd(&stats0[b * SPAD + 1], sq);
    }
}

// ---------------------------------------------------------------------------
// K2: LN0-normalize + depthwise 7x7 conv on the 7x7 map, one WAVE per (b,c).
// ---------------------------------------------------------------------------
__global__ __launch_bounds__(512) void mid_kernel(
    const float* __restrict__ p0,
    const float* __restrict__ ln0w, const float* __restrict__ ln0b,
    const float* __restrict__ w0,
    const float* __restrict__ stats0,
    float* __restrict__ q1,
    float* __restrict__ stats1)
{
    int tid  = threadIdx.x;
    int lane = tid & 63;
    int bc   = blockIdx.x * 8 + (tid >> 6);
    int b = bc / CC;
    int c = bc - b * CC;

    float s0   = stats0[b * SPAD + 0];
    float ss0  = stats0[b * SPAD + 1];
    float mean = s0 * (1.f / CKK);
    float rstd = rsqrtf(ss0 * (1.f / CKK) - mean * mean + 1e-5f);

    float val = 0.f;
    if (lane < KK)
        val = (p0[bc * KK + lane] - mean) * rstd * ln0w[c * KK + lane]
              + ln0b[c * KK + lane];

    int i0 = lane / KS;
    int j0 = lane - i0 * KS;
    const float* wc = w0 + c * KK;

    float acc = 0.f;
#pragma unroll
    for (int u = 0; u < KS; ++u) {
        int ii = i0 + u - 3;
#pragma unroll
        for (int v = 0; v < KS; ++v) {
            int jj = j0 + v - 3;
            bool ok = (ii >= 0) && (ii < KS) && (jj >= 0) && (jj < KS);
            int sl = ok ? (ii * KS + jj) : 0;
            float sv = __shfl(val, sl, 64);
            acc += ok ? sv * wc[u * KS + v] : 0.f;
        }
    }
    if (lane >= KK) acc = 0.f;
    if (lane < KK) q1[bc * KK + lane] = acc;

    float s2 = acc, ss2 = acc * acc;
#pragma unroll
    for (int o = 32; o > 0; o >>= 1) {
        s2  += __shfl_down(s2, o, 64);
        ss2 += __shfl_down(ss2, o, 64);
    }
    if (lane == 0) {
        atomicAdd(&stats1[b * SPAD + 0], s2);
        atomicAdd(&stats1[b * SPAD + 1], ss2);
    }
}

// ---------------------------------------------------------------------------
// K3: fused LN1+ReLU taps + per-(b,c) depthwise 7x7 SAME conv.
// Row-pair-packed LDS: cell[r2][pc] = {xp[2r2][pc], xp[2r2+1][pc]} (f2, 8B
// aligned -> guaranteed ds_read_b64, contiguous 512B/wave = conflict-free).
// Lane owns output col `lane`, 14 rows as 7 packed f2 accumulators.
// Per (s,t,v): 2 v_pk_fma_f32 (diag + op_sel-swapped cross) cover all four
// (input row, output row) tap combos. 70 b64 reads + ~400 pkfma per wave.
// ---------------------------------------------------------------------------
#define TW2 64     // cells per packed row-pair

__device__ __forceinline__ float rfl(float v) {
    return __int_as_float(__builtin_amdgcn_readfirstlane(__float_as_int(v)));
}

// acc.lo += vp.lo*tp.lo ; acc.hi += vp.hi*tp.lo   (diag, tap in lo half)
__device__ __forceinline__ void pkfma_dl(f2& acc, f2 vp, f2 tp) {
    asm("v_pk_fma_f32 %0, %1, %2, %0 op_sel_hi:[1,0,1]"
        : "+v"(acc) : "v"(vp), "v"(tp));
}
// acc.lo += vp.lo*tp.hi ; acc.hi += vp.hi*tp.hi   (diag, tap in hi half)
__device__ __forceinline__ void pkfma_dh(f2& acc, f2 vp, f2 tp) {
    asm("v_pk_fma_f32 %0, %1, %2, %0 op_sel:[0,1,0] op_sel_hi:[1,1,1]"
        : "+v"(acc) : "v"(vp), "v"(tp));
}
// acc.lo += vp.hi*tp.lo ; acc.hi += vp.lo*tp.hi   (cross, swapped rows)
__device__ __forceinline__ void pkfma_x(f2& acc, f2 vp, f2 tp) {
    asm("v_pk_fma_f32 %0, %1, %2, %0 op_sel:[1,0,0] op_sel_hi:[0,1,1]"
        : "+v"(acc) : "v"(vp), "s"(tp));
}

__global__ __launch_bounds__(256) void conv_kernel(
    const float* __restrict__ x,
    const float* __restrict__ q1, const float* __restrict__ stats1,
    const float* __restrict__ ln1w, const float* __restrict__ ln1b,
    float* __restrict__ out)
{
    __shared__ f2 tile2[32 * TW2];   // 16 KB; padded row pr = x row pr-3, 0 outside
    __shared__ float kt[KK];
    __shared__ f2 dtab[16];          // diag tap pairs  [d][j]: {kt[2d*7+2j], kt[2d*7+2j+1]|0}
    __shared__ f2 ctab[28];          // cross tap pairs [d][v]: {kt[(2d+1)*7+v]|0, kt[(2d-1)*7+v]|0}
    int bc   = blockIdx.x;
    int b    = bc / CC;
    int c    = bc - b * CC;
    int tid  = threadIdx.x;
    int lane = tid & 63;
    int wid  = tid >> 6;

    // ---- taps: LN1 + ReLU on q1 ----
    if (tid < KK) {
        float s1  = stats1[b * SPAD + 0];
        float ss1 = stats1[b * SPAD + 1];
        float m = s1 * (1.f / CKK);
        float r = rsqrtf(ss1 * (1.f / CKK) - m * m + 1e-5f);
        float v = (q1[(size_t)bc * KK + tid] - m) * r * ln1w[c * KK + tid]
                  + ln1b[c * KK + tid];
        kt[tid] = v > 0.f ? v : 0.f;
    }

    // ---- zero the whole packed tile ----
    for (int i = tid; i < 32 * TW2 / 2; i += 256)
        ((float4*)tile2)[i] = make_float4(0.f, 0.f, 0.f, 0.f);
    __syncthreads();   // kt + zeros visible

    // ---- build tap pair tables (from kt) ----
    if (tid < 28) {
        int d = tid / KS, v = tid - KS * d;
        f2 p;
        p.x = (d < 3) ? kt[(2 * d + 1) * KS + v] : 0.f;
        p.y = (d > 0) ? kt[(2 * d - 1) * KS + v] : 0.f;
        ctab[tid] = p;
    } else if (tid < 44) {
        int t = tid - 28;
        int d = t / 4, j = t - 4 * d;
        f2 p;
        p.x = kt[2 * d * KS + 2 * j];
        p.y = (2 * j + 1 < KS) ? kt[2 * d * KS + 2 * j + 1] : 0.f;
        dtab[t] = p;
    }

    // ---- stage x into packed cells: pr = r+3 -> (r2 = pr>>1, half = pr&1) ----
    const float* src = x + (size_t)bc * HW;
    for (int i = tid; i < HH * 14; i += 256) {
        int r = i / 14;
        int q = i - r * 14;
        float4 v4 = *(const float4*)(src + r * WW + q * 4);
        int pr = r + 3;
        float* cell = (float*)(tile2 + (pr >> 1) * TW2 + 3 + 4 * q);
        int h = pr & 1;
        cell[0 + h] = v4.x; cell[2 + h] = v4.y;
        cell[4 + h] = v4.z; cell[6 + h] = v4.w;
    }
    __syncthreads();

    // ---- tap tables -> registers (broadcast b128 reads, then pin) ----
    f2 dp[16], cp[28];
#pragma unroll
    for (int i = 0; i < 8; ++i) {
        float4 t4 = ((const float4*)dtab)[i];
        dp[2 * i]     = (f2){t4.x, t4.y};
        dp[2 * i + 1] = (f2){t4.z, t4.w};
    }
#pragma unroll
    for (int i = 0; i < 14; ++i) {
        float4 t4 = ((const float4*)ctab)[i];
        cp[2 * i]     = (f2){rfl(t4.x), rfl(t4.y)};
        cp[2 * i + 1] = (f2){rfl(t4.z), rfl(t4.w)};
    }

    // ---- main loop: 10 packed row-pair steps, accumulator forwarding ----
    int r0 = wid * 14;
    int R2 = wid * 7;
    f2 acc2[7];
#pragma unroll
    for (int t = 0; t < 7; ++t) acc2[t] = (f2){0.f, 0.f};

#pragma unroll
    for (int s = 0; s < 10; ++s) {
        const f2* cellp = tile2 + (R2 + s) * TW2 + lane;
        f2 v2[KS];
#pragma unroll
        for (int j = 0; j < KS; ++j) v2[j] = cellp[j];   // ds_read_b64, clean
#pragma unroll
        for (int d = 0; d < 4; ++d) {
            int t = s - d;                               // static after unroll
            if (t < 0 || t > 6) continue;
#pragma unroll
            for (int v = 0; v < KS; ++v) {
                if (v & 1) pkfma_dh(acc2[t], v2[v], dp[d * 4 + (v >> 1)]);
                else       pkfma_dl(acc2[t], v2[v], dp[d * 4 + (v >> 1)]);
                pkfma_x(acc2[t], v2[v], cp[d * KS + v]);
            }
        }
    }

    if (lane < WW) {
        float* ob = out + (size_t)bc * HW + r0 * WW + lane;
#pragma unroll
        for (int t = 0; t < 7; ++t) {
            ob[(2 * t) * WW]     = acc2[t].x;
            ob[(2 * t + 1) * WW] = acc2[t].y;
        }
    }
}

// ---------------------------------------------------------------------------
extern "C" void kernel_launch(void* const* d_in, const int* in_sizes, int n_in,
                              void* d_out, int out_size, void* d_ws, size_t ws_size,
                              hipStream_t stream) {
    const float* x    = (const float*)d_in[0];
    const float* ln0w = (const float*)d_in[1];
    const float* ln0b = (const float*)d_in[2];
    const float* w0   = (const float*)d_in[3];
    const float* ln1w = (const float*)d_in[4];
    const float* ln1b = (const float*)d_in[5];
    float* out = (float*)d_out;

    float* p0     = (float*)d_ws;          // [NCELL]
    float* q1     = p0 + NCELL;            // [NCELL]
    float* stats0 = q1 + NCELL;            // [BB*SPAD]
    float* stats1 = stats0 + BB * SPAD;    // [BB*SPAD]

    zero_kernel<<<2 * BB * SPAD / 256, 256, 0, stream>>>(stats0);
    pool_kernel<<<NCELL / 256, 256, 0, stream>>>(x, p0, stats0);
    mid_kernel <<<NBC / 8, 512, 0, stream>>>(p0, ln0w, ln0b, w0, stats0, q1, stats1);
    conv_kernel<<<NBC, 256, 0, stream>>>(x, q1, stats1, ln1w, ln1b, out);
}

// Round 10
// 67.564 us; speedup vs baseline: 1.2154x; 1.2154x over previous
//
#include <hip/hip_runtime.h>

// Problem constants (B,C,H,W,K) = (32,192,56,56,7)
#define BB 32
#define CC 192
#define HH 56
#define WW 56
#define KS 7
#define HW 3136        // 56*56
#define KK 49
#define CKK 9408       // C*K*K
#define PL 8
#define NCELL (BB * CC * KK)   // 301056
#define NBC (BB * CC)          // 6144
#define P0BLK 37               // pool blocks per sample (37*256 >= 9408)
#define MIDBLK 24              // mid blocks per sample

typedef float f2 __attribute__((ext_vector_type(2)));

// ---------------------------------------------------------------------------
// K1: avg pool 56x56 -> 7x7 + per-block LN0 partials (no atomics, no zeroing).
// Grid 32*37; block (b,t) covers cells t*256..+255 of sample b only.
// ---------------------------------------------------------------------------
__global__ __launch_bounds__(256) void pool_kernel(const float* __restrict__ x,
                                                   float* __restrict__ p0,
                                                   float2* __restrict__ part0) {
    __shared__ float red[8];
    int b = blockIdx.x / P0BLK;
    int t = blockIdx.x - b * P0BLK;
    int cell = t * 256 + threadIdx.x;
    float v = 0.f;
    if (cell < CKK) {
        int c = cell / KK;
        int r = cell - c * KK;
        int i = r / KS;
        int j = r - i * KS;
        const float* src = x + ((size_t)(b * CC + c)) * HW + (i * PL) * WW + j * PL;
        float s = 0.f;
#pragma unroll
        for (int a = 0; a < PL; ++a) {
            float4 v0 = *(const float4*)(src + a * WW);
            float4 v1 = *(const float4*)(src + a * WW + 4);
            s += v0.x + v0.y + v0.z + v0.w + v1.x + v1.y + v1.z + v1.w;
        }
        v = s * (1.f / 64.f);
        p0[b * CKK + cell] = v;
    }
    float sv = v, sq = v * v;
#pragma unroll
    for (int o = 32; o > 0; o >>= 1) {
        sv += __shfl_down(sv, o, 64);
        sq += __shfl_down(sq, o, 64);
    }
    if ((threadIdx.x & 63) == 0) {
        red[(threadIdx.x >> 6) * 2 + 0] = sv;
        red[(threadIdx.x >> 6) * 2 + 1] = sq;
    }
    __syncthreads();
    if (threadIdx.x == 0)
        part0[blockIdx.x] = make_float2(red[0] + red[2] + red[4] + red[6],
                                        red[1] + red[3] + red[5] + red[7]);
}

// ---------------------------------------------------------------------------
// K2: LN0-normalize + depthwise 7x7 conv on the 7x7 map, one WAVE per (b,c).
// Stats0 from 37 partials (wave prologue); writes q1 + one LN1 partial/block.
// Grid 768 = b*24 + seg; block 512 = 8 waves = 8 consecutive bc.
// ---------------------------------------------------------------------------
__global__ __launch_bounds__(512) void mid_kernel(
    const float* __restrict__ p0,
    const float* __restrict__ ln0w, const float* __restrict__ ln0b,
    const float* __restrict__ w0,
    const float2* __restrict__ part0,
    float* __restrict__ q1,
    float2* __restrict__ part1)
{
    __shared__ float red[16];
    int tid  = threadIdx.x;
    int lane = tid & 63;
    int bc   = blockIdx.x * 8 + (tid >> 6);
    int b = bc / CC;
    int c = bc - b * CC;

    // ---- stats0 from partials (each wave independently) ----
    float s0 = 0.f, ss0 = 0.f;
    if (lane < P0BLK) {
        float2 p = part0[b * P0BLK + lane];
        s0 = p.x; ss0 = p.y;
    }
#pragma unroll
    for (int o = 32; o > 0; o >>= 1) {
        s0  += __shfl_down(s0, o, 64);
        ss0 += __shfl_down(ss0, o, 64);
    }
    s0  = __shfl(s0, 0, 64);
    ss0 = __shfl(ss0, 0, 64);
    float mean = s0 * (1.f / CKK);
    float rstd = rsqrtf(ss0 * (1.f / CKK) - mean * mean + 1e-5f);

    float val = 0.f;
    if (lane < KK)
        val = (p0[bc * KK + lane] - mean) * rstd * ln0w[c * KK + lane]
              + ln0b[c * KK + lane];

    int i0 = lane / KS;
    int j0 = lane - i0 * KS;
    const float* wc = w0 + c * KK;

    float acc = 0.f;
#pragma unroll
    for (int u = 0; u < KS; ++u) {
        int ii = i0 + u - 3;
#pragma unroll
        for (int v = 0; v < KS; ++v) {
            int jj = j0 + v - 3;
            bool ok = (ii >= 0) && (ii < KS) && (jj >= 0) && (jj < KS);
            int sl = ok ? (ii * KS + jj) : 0;
            float sv = __shfl(val, sl, 64);
            acc += ok ? sv * wc[u * KS + v] : 0.f;
        }
    }
    if (lane >= KK) acc = 0.f;
    if (lane < KK) q1[bc * KK + lane] = acc;

    float s2 = acc, ss2 = acc * acc;
#pragma unroll
    for (int o = 32; o > 0; o >>= 1) {
        s2  += __shfl_down(s2, o, 64);
        ss2 += __shfl_down(ss2, o, 64);
    }
    if (lane == 0) {
        red[(tid >> 6) * 2 + 0] = s2;
        red[(tid >> 6) * 2 + 1] = ss2;
    }
    __syncthreads();
    if (tid == 0) {
        float a = 0.f, q = 0.f;
#pragma unroll
        for (int w = 0; w < 8; ++w) { a += red[2 * w]; q += red[2 * w + 1]; }
        part1[blockIdx.x] = make_float2(a, q);
    }
}

// ---------------------------------------------------------------------------
// K3: fused LN1+ReLU taps + per-(b,c) depthwise 7x7 SAME conv.
// Row-pair-packed LDS (16 KB), ds_read_b64 main loop (R9 structure, passed),
// v_pk_fma_f32 with ALL taps in SGPR pairs; staging via paired ds_write_b64;
// stats1 from 24 partials in the prologue.
// ---------------------------------------------------------------------------
#define TW2 64

__device__ __forceinline__ float rfl(float v) {
    return __int_as_float(__builtin_amdgcn_readfirstlane(__float_as_int(v)));
}

// acc.lo += vp.lo*tp.lo ; acc.hi += vp.hi*tp.lo   (diag, tap lo)
__device__ __forceinline__ void pkfma_dl(f2& acc, f2 vp, f2 tp) {
    asm("v_pk_fma_f32 %0, %1, %2, %0 op_sel_hi:[1,0,1]"
        : "+v"(acc) : "v"(vp), "s"(tp));
}
// acc.lo += vp.lo*tp.hi ; acc.hi += vp.hi*tp.hi   (diag, tap hi)
__device__ __forceinline__ void pkfma_dh(f2& acc, f2 vp, f2 tp) {
    asm("v_pk_fma_f32 %0, %1, %2, %0 op_sel:[0,1,0] op_sel_hi:[1,1,1]"
        : "+v"(acc) : "v"(vp), "s"(tp));
}
// acc.lo += vp.hi*tp.lo ; acc.hi += vp.lo*tp.hi   (cross, swapped rows)
__device__ __forceinline__ void pkfma_x(f2& acc, f2 vp, f2 tp) {
    asm("v_pk_fma_f32 %0, %1, %2, %0 op_sel:[1,0,0] op_sel_hi:[0,1,1]"
        : "+v"(acc) : "v"(vp), "s"(tp));
}

__global__ __launch_bounds__(256) void conv_kernel(
    const float* __restrict__ x,
    const float* __restrict__ q1, const float2* __restrict__ part1,
    const float* __restrict__ ln1w, const float* __restrict__ ln1b,
    float* __restrict__ out)
{
    __shared__ f2 tile2[32 * TW2];   // pair pr2 holds padded rows 2pr2, 2pr2+1
    __shared__ float kt[KK];
    __shared__ f2 dtab[16];
    __shared__ f2 ctab[28];
    int bc   = blockIdx.x;
    int b    = bc / CC;
    int c    = bc - b * CC;
    int tid  = threadIdx.x;
    int lane = tid & 63;
    int wid  = tid >> 6;

    // ---- stats1 from 24 partials (every wave; lanes >= 24 contribute 0) ----
    float s1 = 0.f, ss1 = 0.f;
    if (lane < MIDBLK) {
        float2 p = part1[b * MIDBLK + lane];
        s1 = p.x; ss1 = p.y;
    }
#pragma unroll
    for (int o = 32; o > 0; o >>= 1) {
        s1  += __shfl_down(s1, o, 64);
        ss1 += __shfl_down(ss1, o, 64);
    }
    s1  = __shfl(s1, 0, 64);
    ss1 = __shfl(ss1, 0, 64);

    // ---- taps: LN1 + ReLU on q1 (threads 0..48 = wave 0) ----
    if (tid < KK) {
        float m = s1 * (1.f / CKK);
        float r = rsqrtf(ss1 * (1.f / CKK) - m * m + 1e-5f);
        float v = (q1[(size_t)bc * KK + tid] - m) * r * ln1w[c * KK + tid]
                  + ln1b[c * KK + tid];
        kt[tid] = v > 0.f ? v : 0.f;
    }

    // ---- zero the packed tile ----
    for (int i = tid; i < 32 * TW2 / 2; i += 256)
        ((float4*)tile2)[i] = make_float4(0.f, 0.f, 0.f, 0.f);
    __syncthreads();   // kt + zeros visible

    // ---- tap pair tables ----
    if (tid < 28) {
        int d = tid / KS, v = tid - KS * d;
        f2 p;
        p.x = (d < 3) ? kt[(2 * d + 1) * KS + v] : 0.f;
        p.y = (d > 0) ? kt[(2 * d - 1) * KS + v] : 0.f;
        ctab[tid] = p;
    } else if (tid < 44) {
        int t = tid - 28;
        int d = t / 4, j = t - 4 * d;
        f2 p;
        p.x = kt[2 * d * KS + 2 * j];
        p.y = (2 * j + 1 < KS) ? kt[2 * d * KS + 2 * j + 1] : 0.f;
        dtab[t] = p;
    }

    // ---- stage x as row pairs: task (pr2 1..29, q 0..13) -> 4 ds_write_b64 ----
    const float* src = x + (size_t)bc * HW;
    for (int i = tid; i < 29 * 14; i += 256) {
        int pr2 = 1 + i / 14;
        int q   = i - (pr2 - 1) * 14;
        int rA  = 2 * pr2 - 3;            // odd x row (or -1)
        int rB  = rA + 1;                 // even x row (or 56)
        float4 a4 = (rA >= 0) ? *(const float4*)(src + rA * WW + 4 * q)
                              : make_float4(0.f, 0.f, 0.f, 0.f);
        float4 b4 = (rB < HH) ? *(const float4*)(src + rB * WW + 4 * q)
                              : make_float4(0.f, 0.f, 0.f, 0.f);
        f2* cell = tile2 + pr2 * TW2 + 3 + 4 * q;
        cell[0] = (f2){a4.x, b4.x};
        cell[1] = (f2){a4.y, b4.y};
        cell[2] = (f2){a4.z, b4.z};
        cell[3] = (f2){a4.w, b4.w};
    }
    __syncthreads();

    // ---- tap tables -> SGPR pairs ----
    f2 dp[16], cp[28];
#pragma unroll
    for (int i = 0; i < 8; ++i) {
        float4 t4 = ((const float4*)dtab)[i];
        dp[2 * i]     = (f2){rfl(t4.x), rfl(t4.y)};
        dp[2 * i + 1] = (f2){rfl(t4.z), rfl(t4.w)};
    }
#pragma unroll
    for (int i = 0; i < 14; ++i) {
        float4 t4 = ((const float4*)ctab)[i];
        cp[2 * i]     = (f2){rfl(t4.x), rfl(t4.y)};
        cp[2 * i + 1] = (f2){rfl(t4.z), rfl(t4.w)};
    }

    // ---- main loop: 10 packed row-pair steps, accumulator forwarding ----
    int r0 = wid * 14;
    int R2 = wid * 7;
    f2 acc2[7];
#pragma unroll
    for (int t = 0; t < 7; ++t) acc2[t] = (f2){0.f, 0.f};

#pragma unroll
    for (int s = 0; s < 10; ++s) {
        const f2* cellp = tile2 + (R2 + s) * TW2 + lane;
        f2 v2[KS];
#pragma unroll
        for (int j = 0; j < KS; ++j) v2[j] = cellp[j];   // ds_read_b64
#pragma unroll
        for (int d = 0; d < 4; ++d) {
            int t = s - d;                               // static after unroll
            if (t < 0 || t > 6) continue;
#pragma unroll
            for (int v = 0; v < KS; ++v) {
                if (v & 1) pkfma_dh(acc2[t], v2[v], dp[d * 4 + (v >> 1)]);
                else       pkfma_dl(acc2[t], v2[v], dp[d * 4 + (v >> 1)]);
                pkfma_x(acc2[t], v2[v], cp[d * KS + v]);
            }
        }
    }

    if (lane < WW) {
        float* ob = out + (size_t)bc * HW + r0 * WW + lane;
#pragma unroll
        for (int t = 0; t < 7; ++t) {
            ob[(2 * t) * WW]     = acc2[t].x;
            ob[(2 * t + 1) * WW] = acc2[t].y;
        }
    }
}

// ---------------------------------------------------------------------------
extern "C" void kernel_launch(void* const* d_in, const int* in_sizes, int n_in,
                              void* d_out, int out_size, void* d_ws, size_t ws_size,
                              hipStream_t stream) {
    const float* x    = (const float*)d_in[0];
    const float* ln0w = (const float*)d_in[1];
    const float* ln0b = (const float*)d_in[2];
    const float* w0   = (const float*)d_in[3];
    const float* ln1w = (const float*)d_in[4];
    const float* ln1b = (const float*)d_in[5];
    float* out = (float*)d_out;

    float*  p0    = (float*)d_ws;                    // [NCELL]
    float*  q1    = p0 + NCELL;                      // [NCELL]
    float2* part0 = (float2*)(q1 + NCELL);           // [BB*P0BLK]
    float2* part1 = part0 + BB * P0BLK;              // [BB*MIDBLK]

    pool_kernel<<<BB * P0BLK, 256, 0, stream>>>(x, p0, part0);
    mid_kernel <<<BB * MIDBLK, 512, 0, stream>>>(p0, ln0w, ln0b, w0, part0, q1, part1);
    conv_kernel<<<NBC, 256, 0, stream>>>(x, q1, part1, ln1w, ln1b, out);
}